// Round 1
// baseline (293.047 us; speedup 1.0000x reference)
//
#include <hip/hip_runtime.h>
#include <hip/hip_fp16.h>

// 2-layer GCN via CSR gather built by a two-level counting sort with
// fixed-capacity (padded) coarse buckets:
//   k_init_gcur: gcur[b] = b*CAP
//   k_partition: LDS coarse hist -> scan -> rank tile into LDS-sorted order ->
//                linear coalesced emit (no per-element atomics on the emit)
//   k_bucket:    1024 thr, edges staged once into LDS ev[]; fine hist+scan+place
//                -> ssrc/beg/end/dis (single global read of ebuf)
//   k_gemm1:     g = fp16(dis * (x@W1)), 8 lanes/row
//   k_gather1:   4 lanes/node, 8B (2x half2) gather (unroll x8) + relu + dot(W2) -> t
//   k_gather2:   8 lanes/node scalar gather (unroll x4) -> out
// R8 lesson: per-edge fp32 LDS atomics (ds_add) are ~6x slower than sorted-gather.
// R9 lesson: per-thread sequential row reads are line-complete; gemm1 loads were
// never the bottleneck.
// R10 (this round, no counters — GPU timeout): theory = gather1 dominated by
// redundant lane-loads (8x broadcast ssrc + 8x 4B table loads) and/or L2 thrash
// of the 3.2MB g table by streaming ssrc. Changes: (a) gather1 4 lanes/node with
// 8B loads (same bytes, half the VMEM instrs + half the broadcast redundancy),
// (b) nontemporal hints on all streaming read-once paths so the gather tables
// keep L2 residency.

#define CB 8                  // coarse bucket = col >> CB (256 nodes/bucket)
#define CAP 9216              // max edges per bucket (mean 8192 + 11 sigma)
#define TILE 4096             // edges per partition block (512 thr x 8)

__global__ void k_init_gcur(int* __restrict__ gcur, int nb) {
    int b = blockIdx.x * blockDim.x + threadIdx.x;
    if (b < nb) gcur[b] = b * CAP;
}

// Pack (col&255)<<17 | row  (row < 2^17).
__global__ void __launch_bounds__(512) k_partition(
        const int* __restrict__ row, const int* __restrict__ col,
        int* __restrict__ gcur, int* __restrict__ ebuf, int e, int nb) {
    __shared__ int hist[512];            // counts -> local cursor
    __shared__ int lbase[512];           // exclusive scan (local base)
    __shared__ int gdelta[512];          // gbase[b] - lbase[b]
    __shared__ int sval[TILE];           // tile sorted by bucket
    __shared__ unsigned short sbkt[TILE];
    const int base = blockIdx.x * TILE;
    const int cnt = min(TILE, e - base);
    const int t = threadIdx.x;
    hist[t] = 0;
    __syncthreads();
#pragma unroll
    for (int k = 0; k < TILE / 512; ++k) {
        int i = base + (k << 9) + t;
        if (i < e) atomicAdd(&hist[col[i] >> CB], 1);
    }
    __syncthreads();
    int v = hist[t];
    lbase[t] = v;
    __syncthreads();
    for (int off = 1; off < 512; off <<= 1) {
        int add = (t >= off) ? lbase[t - off] : 0;
        __syncthreads();
        lbase[t] += add;
        __syncthreads();
    }
    int excl = lbase[t] - v;
    __syncthreads();
    lbase[t] = excl;
    int gb = v ? atomicAdd(&gcur[t], v) : 0;   // t >= nb has v == 0
    gdelta[t] = gb - excl;
    hist[t] = excl;                            // local rank cursor
    __syncthreads();
#pragma unroll
    for (int k = 0; k < TILE / 512; ++k) {
        int i = base + (k << 9) + t;
        if (i < e) {
            int c = col[i];
            int r = __builtin_nontemporal_load(&row[i]);  // read-once stream
            int b = c >> CB;
            int p = atomicAdd(&hist[b], 1);
            sval[p] = ((c & ((1 << CB) - 1)) << 17) | r;
            sbkt[p] = (unsigned short)b;
        }
    }
    __syncthreads();
    for (int j = t; j < cnt; j += 512) {       // coalesced emit
        int b = sbkt[j];
        int p = gdelta[b] + j;                 // == gbase[b] + (j - lbase[b])
        if (p < (b + 1) * CAP) ebuf[p] = sval[j];  // overflow guard
    }
}

// One block per bucket, 1024 threads: stage edges into LDS once, fine hist +
// scan (lanes<256, uniform barriers) + place from LDS.
__global__ void __launch_bounds__(1024) k_bucket(
        const int* __restrict__ ebuf, const int* __restrict__ gcur,
        int* __restrict__ begA, int* __restrict__ endA, int* __restrict__ ssrc,
        float* __restrict__ dis, int n) {
    __shared__ int ev[CAP];            // 36 KB staged bucket
    __shared__ int hist[256];
    __shared__ int sc[256];
    const int b = blockIdx.x, t = threadIdx.x;
    const int base = b * CAP;
    const int cnt = min(gcur[b] - base, CAP);
    if (t < 256) hist[t] = 0;
    __syncthreads();
    for (int j = t; j < cnt; j += 1024) {
        int v = __builtin_nontemporal_load(&ebuf[base + j]);  // read-once stream
        ev[j] = v;
        atomicAdd(&hist[v >> 17], 1);
    }
    __syncthreads();
    int v = 0;
    if (t < 256) { v = hist[t]; sc[t] = v; }
    __syncthreads();
    for (int off = 1; off < 256; off <<= 1) {
        int add = 0;
        if (t < 256 && t >= off) add = sc[t - off];
        __syncthreads();
        if (t < 256) sc[t] += add;
        __syncthreads();
    }
    if (t < 256) {
        int excl = sc[t] - v;
        int node = (b << CB) + t;
        if (node < n) {
            begA[node] = base + excl;
            endA[node] = base + excl + v;
            dis[node] = rsqrtf((float)(v + 1));
        }
        hist[t] = excl;  // local cursor
    }
    __syncthreads();
    for (int j = t; j < cnt; j += 1024) {
        int val = ev[j];
        int p = atomicAdd(&hist[val >> 17], 1);
        // nt store: ssrc gets evicted by gemm1's 51MB x-stream before re-use
        __builtin_nontemporal_store(val & 0x1FFFF, &ssrc[base + p]);
    }
}

// g[N,16] (fp16) = dis[row] * (x[N,128] @ W1[128,16]).
// 8 lanes/row: coalesced float4 reads, butterfly reduce, 32B coalesced store.
__global__ void k_gemm1(const float* __restrict__ x, const float* __restrict__ W1,
                        const float* __restrict__ dis, __half* __restrict__ gh, int n) {
    __shared__ float wt[16 * 128];
    for (int t = threadIdx.x; t < 2048; t += blockDim.x) {
        int j = t >> 7, k = t & 127;
        wt[t] = W1[k * 16 + j];
    }
    __syncthreads();
    int t = blockIdx.x * blockDim.x + threadIdx.x;
    if (t >= n * 8) return;
    int r = t >> 3, l = t & 7;
    const float4* x4 = (const float4*)x;
    const float4* w4 = (const float4*)wt;
    float4 va = x4[(size_t)r * 32 + l];
    float4 vb = x4[(size_t)r * 32 + l + 8];
    float4 vc = x4[(size_t)r * 32 + l + 16];
    float4 vd = x4[(size_t)r * 32 + l + 24];
    float acc[16];
#pragma unroll
    for (int j = 0; j < 16; ++j) {
        float4 wa = w4[j * 32 + l];
        float4 wb = w4[j * 32 + l + 8];
        float4 wc = w4[j * 32 + l + 16];
        float4 wd = w4[j * 32 + l + 24];
        acc[j] = va.x * wa.x + va.y * wa.y + va.z * wa.z + va.w * wa.w
               + vb.x * wb.x + vb.y * wb.y + vb.z * wb.z + vb.w * wb.w
               + vc.x * wc.x + vc.y * wc.y + vc.z * wc.z + vc.w * wc.w
               + vd.x * wd.x + vd.y * wd.y + vd.z * wd.z + vd.w * wd.w;
    }
#pragma unroll
    for (int j = 0; j < 16; ++j) {
#pragma unroll
        for (int m = 4; m >= 1; m >>= 1) acc[j] += __shfl_xor(acc[j], m, 8);
    }
    float d = dis[r];
    __half2 hh = __floats2half2_rn(d * acc[2 * l], d * acc[2 * l + 1]);
    ((__half2*)gh)[(size_t)r * 8 + l] = hh;  // 8 lanes -> 32B coalesced
}

// Unpack an 8B load (two half2) and accumulate into 4 fp32 lanes.
__device__ inline void h2acc(float2 r, float& x0, float& x1, float& x2, float& x3) {
    __half2 p = *(__half2*)&r.x, q = *(__half2*)&r.y;
    float2 f0 = __half22float2(p), f1 = __half22float2(q);
    x0 += f0.x; x1 += f0.y; x2 += f1.x; x3 += f1.y;
}

// 4 threads/node, 8B (2x half2) reads: same bytes as before but half the VMEM
// instructions, half the broadcast-redundant ssrc loads, half the reduce depth.
// Edge loop unrolled x8 so 8 random loads are in flight per thread.
__global__ void k_gather1(const int* __restrict__ begA, const int* __restrict__ endA,
                          const int* __restrict__ ssrc,
                          const float2* __restrict__ g4, const float* __restrict__ dis,
                          const float* __restrict__ b1, const float* __restrict__ W2,
                          float* __restrict__ tbuf, int n) {
    int t = blockIdx.x * blockDim.x + threadIdx.x;
    if (t >= n * 4) return;
    int i = t >> 2, l = t & 3;
    float di = dis[i];
    int beg = begA[i], end = endA[i];
    float acc0, acc1, acc2, acc3;               // features 4l .. 4l+3
    {
        float2 s = g4[(size_t)i * 4 + l];       // self-loop
        __half2 p = *(__half2*)&s.x, q = *(__half2*)&s.y;
        float2 f0 = __half22float2(p), f1 = __half22float2(q);
        acc0 = f0.x; acc1 = f0.y; acc2 = f1.x; acc3 = f1.y;
    }
    float bcc0 = 0.f, bcc1 = 0.f, bcc2 = 0.f, bcc3 = 0.f;
    int e = beg;
    for (; e + 8 <= end; e += 8) {
        int s0 = __builtin_nontemporal_load(&ssrc[e + 0]);
        int s1 = __builtin_nontemporal_load(&ssrc[e + 1]);
        int s2 = __builtin_nontemporal_load(&ssrc[e + 2]);
        int s3 = __builtin_nontemporal_load(&ssrc[e + 3]);
        int s4 = __builtin_nontemporal_load(&ssrc[e + 4]);
        int s5 = __builtin_nontemporal_load(&ssrc[e + 5]);
        int s6 = __builtin_nontemporal_load(&ssrc[e + 6]);
        int s7 = __builtin_nontemporal_load(&ssrc[e + 7]);
        float2 r0 = g4[(size_t)s0 * 4 + l];
        float2 r1 = g4[(size_t)s1 * 4 + l];
        float2 r2 = g4[(size_t)s2 * 4 + l];
        float2 r3 = g4[(size_t)s3 * 4 + l];
        float2 r4 = g4[(size_t)s4 * 4 + l];
        float2 r5 = g4[(size_t)s5 * 4 + l];
        float2 r6 = g4[(size_t)s6 * 4 + l];
        float2 r7 = g4[(size_t)s7 * 4 + l];
        h2acc(r0, acc0, acc1, acc2, acc3);
        h2acc(r1, bcc0, bcc1, bcc2, bcc3);
        h2acc(r2, acc0, acc1, acc2, acc3);
        h2acc(r3, bcc0, bcc1, bcc2, bcc3);
        h2acc(r4, acc0, acc1, acc2, acc3);
        h2acc(r5, bcc0, bcc1, bcc2, bcc3);
        h2acc(r6, acc0, acc1, acc2, acc3);
        h2acc(r7, bcc0, bcc1, bcc2, bcc3);
    }
    for (; e < end; ++e) {
        int s = __builtin_nontemporal_load(&ssrc[e]);
        float2 r = g4[(size_t)s * 4 + l];
        h2acc(r, acc0, acc1, acc2, acc3);
    }
    acc0 += bcc0; acc1 += bcc1; acc2 += bcc2; acc3 += bcc3;
    int f = l * 4;
    float u = fmaxf(di * acc0 + b1[f + 0], 0.f) * W2[f + 0]
            + fmaxf(di * acc1 + b1[f + 1], 0.f) * W2[f + 1]
            + fmaxf(di * acc2 + b1[f + 2], 0.f) * W2[f + 2]
            + fmaxf(di * acc3 + b1[f + 3], 0.f) * W2[f + 3];
    u += __shfl_xor(u, 2, 4);
    u += __shfl_xor(u, 1, 4);
    if (l == 0) tbuf[i] = di * u;
}

// 8 threads/node, lane-strided edges (coalesced ssrc), unroll x4 for MLP:
// out[i] = dis[i] * (sum_e t[src] + t[i]) + b2
__global__ void k_gather2(const int* __restrict__ begA, const int* __restrict__ endA,
                          const int* __restrict__ ssrc,
                          const float* __restrict__ tbuf, const float* __restrict__ dis,
                          const float* __restrict__ b2, float* __restrict__ out, int n) {
    int t = blockIdx.x * blockDim.x + threadIdx.x;
    if (t >= n * 8) return;
    int i = t >> 3, l = t & 7;
    int beg = begA[i], end = endA[i];
    float acc = (l == 0) ? tbuf[i] : 0.f;
    float acc1 = 0.f;
    int e = beg + l;
    for (; e + 24 < end; e += 32) {
        int s0 = __builtin_nontemporal_load(&ssrc[e]);
        int s1 = __builtin_nontemporal_load(&ssrc[e + 8]);
        int s2 = __builtin_nontemporal_load(&ssrc[e + 16]);
        int s3 = __builtin_nontemporal_load(&ssrc[e + 24]);
        float v0 = tbuf[s0], v1 = tbuf[s1], v2 = tbuf[s2], v3 = tbuf[s3];
        acc += v0; acc1 += v1; acc += v2; acc1 += v3;
    }
    for (; e < end; e += 8) acc += tbuf[__builtin_nontemporal_load(&ssrc[e])];
    acc += acc1;
#pragma unroll
    for (int m = 4; m >= 1; m >>= 1) acc += __shfl_xor(acc, m, 8);
    if (l == 0) out[i] = dis[i] * acc + b2[0];
}

extern "C" void kernel_launch(void* const* d_in, const int* in_sizes, int n_in,
                              void* d_out, int out_size, void* d_ws, size_t ws_size,
                              hipStream_t stream) {
    const float* x  = (const float*)d_in[0];
    const int*   ei = (const int*)d_in[1];
    const float* W1 = (const float*)d_in[2];
    const float* b1 = (const float*)d_in[3];
    const float* W2 = (const float*)d_in[4];
    const float* b2 = (const float*)d_in[5];
    float* out = (float*)d_out;

    const int N = in_sizes[0] / 128;   // 100000
    const int E = in_sizes[1] / 2;     // 3200000
    const int* row = ei;        // edge_index[0] = source
    const int* col = ei + E;    // edge_index[1] = target
    const int NB = (N + 255) >> CB;    // coarse buckets (391)
    const size_t PADE = (size_t)NB * CAP;  // padded edge capacity

    // workspace (4B units): ebuf[PADE] (aliased by gh fp16 after k_bucket) |
    // ssrc[PADE] | dis[N] | tbuf[N] | begA[N] | endA[N] | gcur[512]
    size_t bigsz = PADE > (size_t)N * 8 ? PADE : (size_t)N * 8;
    int*    ebuf = (int*)d_ws;
    __half* gh   = (__half*)d_ws;      // aliases ebuf (dead before k_gemm1)
    int*    ssrc = (int*)d_ws + bigsz;
    float*  dis  = (float*)(ssrc + PADE);
    float*  tbuf = dis + N;
    int*    begA = (int*)(tbuf + N);
    int*    endA = begA + N;
    int*    gcur = endA + N;

    auto cdiv = [](int a, int b) { return (a + b - 1) / b; };

    k_init_gcur<<<cdiv(NB, 256),    256,  0, stream>>>(gcur, NB);
    k_partition<<<cdiv(E, TILE),    512,  0, stream>>>(row, col, gcur, ebuf, E, NB);
    k_bucket   <<<NB,               1024, 0, stream>>>(ebuf, gcur, begA, endA, ssrc, dis, N);
    k_gemm1    <<<cdiv(N * 8, 256), 256,  0, stream>>>(x, W1, dis, gh, N);
    k_gather1  <<<cdiv(N * 4, 256), 256,  0, stream>>>(begA, endA, ssrc, (const float2*)gh,
                                                       dis, b1, W2, tbuf, N);
    k_gather2  <<<cdiv(N * 8, 256), 256,  0, stream>>>(begA, endA, ssrc, tbuf, dis, b2, out, N);
}

// Round 5
// 214.295 us; speedup vs baseline: 1.3675x; 1.3675x over previous
//
#include <hip/hip_runtime.h>
#include <hip/hip_fp16.h>

// 2-layer GCN via CSR gather built by a two-level counting sort with
// fixed-capacity (padded) coarse buckets:
//   k_init_gcur: gcur[b] = b*CAP
//   k_partition: LDS coarse hist -> scan -> rank tile into LDS-sorted order ->
//                linear coalesced emit (no per-element atomics on the emit)
//   k_bucket:    1024 thr, edges staged once into LDS ev[]; fine hist+scan+place
//                -> ssrc/beg/end/dis (single global read of ebuf)
//   k_gemm1:     g = fp16(dis * (x@W1)), 8 lanes/row
//   k_gather1:   4 lanes/node, 8B (2x half2) gather (unroll x8) + relu + dot(W2) -> t
//   k_gather2:   8 lanes/node scalar gather (unroll x4) -> out
// R8 lesson: per-edge fp32 LDS atomics (ds_add) are ~6x slower than sorted-gather.
// R9 lesson: per-thread sequential row reads are line-complete; gemm1 loads were
// never the bottleneck.
// R10 lesson (counters): __builtin_nontemporal_store on SCATTERED 4B writes
// (ssrc placement) defeats L2 write-combining -> 148MB HBM writes for a 13MB
// array, k_bucket 80us write-BW-bound. nt is only for full-line streaming
// writes. All nt hints reverted.
// R11: single diff vs 210us baseline = gather1 at 4 lanes/node with 8B loads
// (half VMEM instrs, half broadcast ssrc redundancy, half reduce depth).
// R12-R14: identical resubmits — three consecutive infra failures (container
// x2, broker timeout x2); no counters; do not stack untested changes.

#define CB 8                  // coarse bucket = col >> CB (256 nodes/bucket)
#define CAP 9216              // max edges per bucket (mean 8192 + 11 sigma)
#define TILE 4096             // edges per partition block (512 thr x 8)

__global__ void k_init_gcur(int* __restrict__ gcur, int nb) {
    int b = blockIdx.x * blockDim.x + threadIdx.x;
    if (b < nb) gcur[b] = b * CAP;
}

// Pack (col&255)<<17 | row  (row < 2^17).
__global__ void __launch_bounds__(512) k_partition(
        const int* __restrict__ row, const int* __restrict__ col,
        int* __restrict__ gcur, int* __restrict__ ebuf, int e, int nb) {
    __shared__ int hist[512];            // counts -> local cursor
    __shared__ int lbase[512];           // exclusive scan (local base)
    __shared__ int gdelta[512];          // gbase[b] - lbase[b]
    __shared__ int sval[TILE];           // tile sorted by bucket
    __shared__ unsigned short sbkt[TILE];
    const int base = blockIdx.x * TILE;
    const int cnt = min(TILE, e - base);
    const int t = threadIdx.x;
    hist[t] = 0;
    __syncthreads();
#pragma unroll
    for (int k = 0; k < TILE / 512; ++k) {
        int i = base + (k << 9) + t;
        if (i < e) atomicAdd(&hist[col[i] >> CB], 1);
    }
    __syncthreads();
    int v = hist[t];
    lbase[t] = v;
    __syncthreads();
    for (int off = 1; off < 512; off <<= 1) {
        int add = (t >= off) ? lbase[t - off] : 0;
        __syncthreads();
        lbase[t] += add;
        __syncthreads();
    }
    int excl = lbase[t] - v;
    __syncthreads();
    lbase[t] = excl;
    int gb = v ? atomicAdd(&gcur[t], v) : 0;   // t >= nb has v == 0
    gdelta[t] = gb - excl;
    hist[t] = excl;                            // local rank cursor
    __syncthreads();
#pragma unroll
    for (int k = 0; k < TILE / 512; ++k) {
        int i = base + (k << 9) + t;
        if (i < e) {
            int c = col[i], r = row[i];
            int b = c >> CB;
            int p = atomicAdd(&hist[b], 1);
            sval[p] = ((c & ((1 << CB) - 1)) << 17) | r;
            sbkt[p] = (unsigned short)b;
        }
    }
    __syncthreads();
    for (int j = t; j < cnt; j += 512) {       // coalesced emit
        int b = sbkt[j];
        int p = gdelta[b] + j;                 // == gbase[b] + (j - lbase[b])
        if (p < (b + 1) * CAP) ebuf[p] = sval[j];  // overflow guard
    }
}

// One block per bucket, 1024 threads: stage edges into LDS once, fine hist +
// scan (lanes<256, uniform barriers) + place from LDS.
__global__ void __launch_bounds__(1024) k_bucket(
        const int* __restrict__ ebuf, const int* __restrict__ gcur,
        int* __restrict__ begA, int* __restrict__ endA, int* __restrict__ ssrc,
        float* __restrict__ dis, int n) {
    __shared__ int ev[CAP];            // 36 KB staged bucket
    __shared__ int hist[256];
    __shared__ int sc[256];
    const int b = blockIdx.x, t = threadIdx.x;
    const int base = b * CAP;
    const int cnt = min(gcur[b] - base, CAP);
    if (t < 256) hist[t] = 0;
    __syncthreads();
    for (int j = t; j < cnt; j += 1024) {
        int v = ebuf[base + j];
        ev[j] = v;
        atomicAdd(&hist[v >> 17], 1);
    }
    __syncthreads();
    int v = 0;
    if (t < 256) { v = hist[t]; sc[t] = v; }
    __syncthreads();
    for (int off = 1; off < 256; off <<= 1) {
        int add = 0;
        if (t < 256 && t >= off) add = sc[t - off];
        __syncthreads();
        if (t < 256) sc[t] += add;
        __syncthreads();
    }
    if (t < 256) {
        int excl = sc[t] - v;
        int node = (b << CB) + t;
        if (node < n) {
            begA[node] = base + excl;
            endA[node] = base + excl + v;
            dis[node] = rsqrtf((float)(v + 1));
        }
        hist[t] = excl;  // local cursor
    }
    __syncthreads();
    for (int j = t; j < cnt; j += 1024) {
        int val = ev[j];
        int p = atomicAdd(&hist[val >> 17], 1);
        ssrc[base + p] = val & 0x1FFFF;    // scattered 4B: MUST stay cached (R10)
    }
}

// g[N,16] (fp16) = dis[row] * (x[N,128] @ W1[128,16]).
// 8 lanes/row: coalesced float4 reads, butterfly reduce, 32B coalesced store.
__global__ void k_gemm1(const float* __restrict__ x, const float* __restrict__ W1,
                        const float* __restrict__ dis, __half* __restrict__ gh, int n) {
    __shared__ float wt[16 * 128];
    for (int t = threadIdx.x; t < 2048; t += blockDim.x) {
        int j = t >> 7, k = t & 127;
        wt[t] = W1[k * 16 + j];
    }
    __syncthreads();
    int t = blockIdx.x * blockDim.x + threadIdx.x;
    if (t >= n * 8) return;
    int r = t >> 3, l = t & 7;
    const float4* x4 = (const float4*)x;
    const float4* w4 = (const float4*)wt;
    float4 va = x4[(size_t)r * 32 + l];
    float4 vb = x4[(size_t)r * 32 + l + 8];
    float4 vc = x4[(size_t)r * 32 + l + 16];
    float4 vd = x4[(size_t)r * 32 + l + 24];
    float acc[16];
#pragma unroll
    for (int j = 0; j < 16; ++j) {
        float4 wa = w4[j * 32 + l];
        float4 wb = w4[j * 32 + l + 8];
        float4 wc = w4[j * 32 + l + 16];
        float4 wd = w4[j * 32 + l + 24];
        acc[j] = va.x * wa.x + va.y * wa.y + va.z * wa.z + va.w * wa.w
               + vb.x * wb.x + vb.y * wb.y + vb.z * wb.z + vb.w * wb.w
               + vc.x * wc.x + vc.y * wc.y + vc.z * wc.z + vc.w * wc.w
               + vd.x * wd.x + vd.y * wd.y + vd.z * wd.z + vd.w * wd.w;
    }
#pragma unroll
    for (int j = 0; j < 16; ++j) {
#pragma unroll
        for (int m = 4; m >= 1; m >>= 1) acc[j] += __shfl_xor(acc[j], m, 8);
    }
    float d = dis[r];
    __half2 hh = __floats2half2_rn(d * acc[2 * l], d * acc[2 * l + 1]);
    ((__half2*)gh)[(size_t)r * 8 + l] = hh;  // 8 lanes -> 32B coalesced
}

// Unpack an 8B load (two half2) and accumulate into 4 fp32 lanes.
__device__ inline void h2acc(float2 r, float& x0, float& x1, float& x2, float& x3) {
    __half2 p = *(__half2*)&r.x, q = *(__half2*)&r.y;
    float2 f0 = __half22float2(p), f1 = __half22float2(q);
    x0 += f0.x; x1 += f0.y; x2 += f1.x; x3 += f1.y;
}

// 4 threads/node, 8B (2x half2) reads: same bytes as the 8-lane version but
// half the VMEM instructions, half the broadcast-redundant ssrc loads, half
// the reduce depth. Edge loop unrolled x8 so 8 random loads are in flight.
__global__ void k_gather1(const int* __restrict__ begA, const int* __restrict__ endA,
                          const int* __restrict__ ssrc,
                          const float2* __restrict__ g4, const float* __restrict__ dis,
                          const float* __restrict__ b1, const float* __restrict__ W2,
                          float* __restrict__ tbuf, int n) {
    int t = blockIdx.x * blockDim.x + threadIdx.x;
    if (t >= n * 4) return;
    int i = t >> 2, l = t & 3;
    float di = dis[i];
    int beg = begA[i], end = endA[i];
    float acc0, acc1, acc2, acc3;               // features 4l .. 4l+3
    {
        float2 s = g4[(size_t)i * 4 + l];       // self-loop
        __half2 p = *(__half2*)&s.x, q = *(__half2*)&s.y;
        float2 f0 = __half22float2(p), f1 = __half22float2(q);
        acc0 = f0.x; acc1 = f0.y; acc2 = f1.x; acc3 = f1.y;
    }
    float bcc0 = 0.f, bcc1 = 0.f, bcc2 = 0.f, bcc3 = 0.f;
    int e = beg;
    for (; e + 8 <= end; e += 8) {
        int s0 = ssrc[e + 0], s1 = ssrc[e + 1], s2 = ssrc[e + 2], s3 = ssrc[e + 3];
        int s4 = ssrc[e + 4], s5 = ssrc[e + 5], s6 = ssrc[e + 6], s7 = ssrc[e + 7];
        float2 r0 = g4[(size_t)s0 * 4 + l];
        float2 r1 = g4[(size_t)s1 * 4 + l];
        float2 r2 = g4[(size_t)s2 * 4 + l];
        float2 r3 = g4[(size_t)s3 * 4 + l];
        float2 r4 = g4[(size_t)s4 * 4 + l];
        float2 r5 = g4[(size_t)s5 * 4 + l];
        float2 r6 = g4[(size_t)s6 * 4 + l];
        float2 r7 = g4[(size_t)s7 * 4 + l];
        h2acc(r0, acc0, acc1, acc2, acc3);
        h2acc(r1, bcc0, bcc1, bcc2, bcc3);
        h2acc(r2, acc0, acc1, acc2, acc3);
        h2acc(r3, bcc0, bcc1, bcc2, bcc3);
        h2acc(r4, acc0, acc1, acc2, acc3);
        h2acc(r5, bcc0, bcc1, bcc2, bcc3);
        h2acc(r6, acc0, acc1, acc2, acc3);
        h2acc(r7, bcc0, bcc1, bcc2, bcc3);
    }
    for (; e < end; ++e) {
        int s = ssrc[e];
        float2 r = g4[(size_t)s * 4 + l];
        h2acc(r, acc0, acc1, acc2, acc3);
    }
    acc0 += bcc0; acc1 += bcc1; acc2 += bcc2; acc3 += bcc3;
    int f = l * 4;
    float u = fmaxf(di * acc0 + b1[f + 0], 0.f) * W2[f + 0]
            + fmaxf(di * acc1 + b1[f + 1], 0.f) * W2[f + 1]
            + fmaxf(di * acc2 + b1[f + 2], 0.f) * W2[f + 2]
            + fmaxf(di * acc3 + b1[f + 3], 0.f) * W2[f + 3];
    u += __shfl_xor(u, 2, 4);
    u += __shfl_xor(u, 1, 4);
    if (l == 0) tbuf[i] = di * u;
}

// 8 threads/node, lane-strided edges (coalesced ssrc), unroll x4 for MLP:
// out[i] = dis[i] * (sum_e t[src] + t[i]) + b2
__global__ void k_gather2(const int* __restrict__ begA, const int* __restrict__ endA,
                          const int* __restrict__ ssrc,
                          const float* __restrict__ tbuf, const float* __restrict__ dis,
                          const float* __restrict__ b2, float* __restrict__ out, int n) {
    int t = blockIdx.x * blockDim.x + threadIdx.x;
    if (t >= n * 8) return;
    int i = t >> 3, l = t & 7;
    int beg = begA[i], end = endA[i];
    float acc = (l == 0) ? tbuf[i] : 0.f;
    float acc1 = 0.f;
    int e = beg + l;
    for (; e + 24 < end; e += 32) {
        int s0 = ssrc[e], s1 = ssrc[e + 8], s2 = ssrc[e + 16], s3 = ssrc[e + 24];
        float v0 = tbuf[s0], v1 = tbuf[s1], v2 = tbuf[s2], v3 = tbuf[s3];
        acc += v0; acc1 += v1; acc += v2; acc1 += v3;
    }
    for (; e < end; e += 8) acc += tbuf[ssrc[e]];
    acc += acc1;
#pragma unroll
    for (int m = 4; m >= 1; m >>= 1) acc += __shfl_xor(acc, m, 8);
    if (l == 0) out[i] = dis[i] * acc + b2[0];
}

extern "C" void kernel_launch(void* const* d_in, const int* in_sizes, int n_in,
                              void* d_out, int out_size, void* d_ws, size_t ws_size,
                              hipStream_t stream) {
    const float* x  = (const float*)d_in[0];
    const int*   ei = (const int*)d_in[1];
    const float* W1 = (const float*)d_in[2];
    const float* b1 = (const float*)d_in[3];
    const float* W2 = (const float*)d_in[4];
    const float* b2 = (const float*)d_in[5];
    float* out = (float*)d_out;

    const int N = in_sizes[0] / 128;   // 100000
    const int E = in_sizes[1] / 2;     // 3200000
    const int* row = ei;        // edge_index[0] = source
    const int* col = ei + E;    // edge_index[1] = target
    const int NB = (N + 255) >> CB;    // coarse buckets (391)
    const size_t PADE = (size_t)NB * CAP;  // padded edge capacity

    // workspace (4B units): ebuf[PADE] (aliased by gh fp16 after k_bucket) |
    // ssrc[PADE] | dis[N] | tbuf[N] | begA[N] | endA[N] | gcur[512]
    size_t bigsz = PADE > (size_t)N * 8 ? PADE : (size_t)N * 8;
    int*    ebuf = (int*)d_ws;
    __half* gh   = (__half*)d_ws;      // aliases ebuf (dead before k_gemm1)
    int*    ssrc = (int*)d_ws + bigsz;
    float*  dis  = (float*)(ssrc + PADE);
    float*  tbuf = dis + N;
    int*    begA = (int*)(tbuf + N);
    int*    endA = begA + N;
    int*    gcur = endA + N;

    auto cdiv = [](int a, int b) { return (a + b - 1) / b; };

    k_init_gcur<<<cdiv(NB, 256),    256,  0, stream>>>(gcur, NB);
    k_partition<<<cdiv(E, TILE),    512,  0, stream>>>(row, col, gcur, ebuf, E, NB);
    k_bucket   <<<NB,               1024, 0, stream>>>(ebuf, gcur, begA, endA, ssrc, dis, N);
    k_gemm1    <<<cdiv(N * 8, 256), 256,  0, stream>>>(x, W1, dis, gh, N);
    k_gather1  <<<cdiv(N * 4, 256), 256,  0, stream>>>(begA, endA, ssrc, (const float2*)gh,
                                                       dis, b1, W2, tbuf, N);
    k_gather2  <<<cdiv(N * 8, 256), 256,  0, stream>>>(begA, endA, ssrc, tbuf, dis, b2, out, N);
}